// Round 8
// baseline (344.243 us; speedup 1.0000x reference)
//
#include <hip/hip_runtime.h>

#define NB 256              // histogram bins
#define NCH 48              // B*C = 16*3
#define HW (1024*1024)      // elements per channel
#define WPC (HW / 4)        // packed words per channel = 262144
#define THREADS 256
#define BPC 64              // blocks per channel -> 3072 blocks per big kernel
#define N4 (WPC / BPC)      // packed words per block = 4096
#define NTILE (N4 / (4 * THREADS))   // 4 uint4-tiles of 1024 words per block

// Native clang vector types: __builtin_nontemporal_* rejects
// HIP_vector_type, but accepts ext_vector_type.
typedef float  nf4 __attribute__((ext_vector_type(4)));

// R8: R6 streaming structure, but ALL cross-block RMW removed.
//   R7 post-mortem: LDS bank replication neutral -> LDS not critical path.
//   Remaining non-streaming work in the ~112 us controllable region:
//     (a) 786K LLC atomicAdds to ghist at end of K1 (serialized at the
//         coherence point, all blocks flushing at once),
//     (b) K3's redundant per-block CDF scan: 3072 x (256 ghist loads +
//         16-barrier scan) before any streaming starts,
//     (c) the 48 KB memset dispatch.
//   Changes:
//     * K1 stores its block histogram to a DISTINCT partial row
//       (part[blk][bin], plain coalesced stores, no atomics, no pre-zero)
//     * new tiny K2 (48 blocks): sum 64 partials/channel + scan -> lutg
//     * K3: no scan; load 256-float LUT and stream
//     * no memset dispatch (all ws buffers fully written before read)
//   Streaming pattern (nt x-loads, cacheable q, nt y-stores) is byte-
//   identical to R6; LDS layouts reverted to R6's simple form.

__device__ __forceinline__ int quant255(float v) {
    v = fminf(fmaxf(v, 0.0f), 1.0f);
    int q = (int)(v * 255.0f);     // fp32 mul + trunc, same as jnp
    q = q < 0 ? 0 : q;
    q = q > 255 ? 255 : q;
    return q;
}

// ---------------- K1: quantize + per-block LDS hist -> partial row --------
__global__ __launch_bounds__(THREADS, 8) void hist_quant_kernel(
    const float* __restrict__ x, unsigned int* __restrict__ part,
    unsigned int* __restrict__ q) {
    __shared__ unsigned int lh[4 * NB];   // one 256-bin sub-hist per wave
    const int t = threadIdx.x;
    const int w = t >> 6;
    for (int i = t; i < 4 * NB; i += THREADS) lh[i] = 0u;
    __syncthreads();

    const int ch  = blockIdx.x / BPC;
    const int blk = blockIdx.x % BPC;
    const nf4* xp = (const nf4*)x + (size_t)ch * WPC;
    unsigned int* qp = q + (size_t)ch * WPC;
    const int base = blk * N4;

    for (int tile = 0; tile < NTILE; ++tile) {
        const int tb = base + tile * (4 * THREADS);
        unsigned pw[4];
        #pragma unroll
        for (int k = 0; k < 4; ++k) {
            // nontemporal: x is read exactly once across the whole pipeline
            nf4 v = __builtin_nontemporal_load(xp + tb + k * THREADS + t);
            int q0 = quant255(v.x), q1 = quant255(v.y);
            int q2 = quant255(v.z), q3 = quant255(v.w);
            atomicAdd(&lh[w * NB + q0], 1u);
            atomicAdd(&lh[w * NB + q1], 1u);
            atomicAdd(&lh[w * NB + q2], 1u);
            atomicAdd(&lh[w * NB + q3], 1u);
            pw[k] = (unsigned)q0 | ((unsigned)q1 << 8)
                  | ((unsigned)q2 << 16) | ((unsigned)q3 << 24);
        }
        // one 16 B unit-stride CACHEABLE store: q stays L3-resident for K3
        ((uint4*)(qp + tb))[t] = make_uint4(pw[0], pw[1], pw[2], pw[3]);
    }
    __syncthreads();

    // Block hist -> OWN partial row: plain coalesced store, no atomics.
    unsigned int s = lh[t] + lh[NB + t] + lh[2 * NB + t] + lh[3 * NB + t];
    part[(size_t)blockIdx.x * NB + t] = s;
}

// ---------------- K2: sum partials + CDF scan -> normalized LUT -----------
__global__ __launch_bounds__(THREADS) void lut_build_kernel(
    const unsigned int* __restrict__ part, float* __restrict__ lutg) {
    __shared__ float sbuf[NB];
    const int t  = threadIdx.x;
    const int ch = blockIdx.x;

    // Sum 64 partial rows of this channel. Lane t reads word t of each
    // 1 KB row -> consecutive lanes, consecutive addresses: coalesced,
    // L2/L3-hot (3 MB table).
    const unsigned int* pp = part + (size_t)ch * BPC * NB;
    unsigned int s = 0;
    #pragma unroll 8
    for (int b = 0; b < BPC; ++b) s += pp[b * NB + t];

    sbuf[t] = (float)s;                   // ints < 2^24 -> exact fp32
    __syncthreads();
    for (int off = 1; off < NB; off <<= 1) {
        float add = (t >= off) ? sbuf[t - off] : 0.0f;
        __syncthreads();
        sbuf[t] += add;
        __syncthreads();
    }
    float total = sbuf[NB - 1];
    lutg[ch * NB + t] = sbuf[t] / fmaxf(total, 1.0f);
}

// ---------------- K3: remap q through LUT -> y ----------------------------
__global__ __launch_bounds__(THREADS, 8) void remap_kernel(
    const unsigned int* __restrict__ q, const float* __restrict__ lutg,
    float* __restrict__ y) {
    __shared__ float lut[NB];
    const int t   = threadIdx.x;
    const int ch  = blockIdx.x / BPC;
    const int blk = blockIdx.x % BPC;

    lut[t] = lutg[ch * NB + t];           // THREADS == NB: one load each
    __syncthreads();

    const unsigned int* qp = q + (size_t)ch * WPC;
    nf4*                yp = (nf4*)y + (size_t)ch * WPC;
    const int base = blk * N4;

    for (int tile = 0; tile < NTILE; ++tile) {
        const int tb = base + tile * (4 * THREADS);
        uint4 pk = ((const uint4*)(qp + tb))[t];   // cacheable: L3 hit
        unsigned pw[4] = {pk.x, pk.y, pk.z, pk.w};
        #pragma unroll
        for (int k = 0; k < 4; ++k) {
            unsigned p = pw[k];
            nf4 o;
            o.x = lut[p & 255];
            o.y = lut[(p >> 8) & 255];
            o.z = lut[(p >> 16) & 255];
            o.w = lut[p >> 24];
            // nontemporal: y is write-once, stream past L3
            __builtin_nontemporal_store(o, yp + tb + k * THREADS + t);
        }
    }
}

extern "C" void kernel_launch(void* const* d_in, const int* in_sizes, int n_in,
                              void* d_out, int out_size, void* d_ws, size_t ws_size,
                              hipStream_t stream) {
    const float* x = (const float*)d_in[0];
    float* y = (float*)d_out;

    // All ws buffers are fully WRITTEN before being read -> no pre-zeroing
    // needed despite the 0xAA poison (memset dispatch removed).
    unsigned int* part = (unsigned int*)d_ws;                         // 3.15 MB
    float*        lutg = (float*)((char*)d_ws + 4  * 1024 * 1024);    // 48 KB
    unsigned int* q    = (unsigned int*)((char*)d_ws + 64 * 1024 * 1024); // 48 MB

    hist_quant_kernel<<<NCH * BPC, THREADS, 0, stream>>>(x, part, q);
    lut_build_kernel <<<NCH,       THREADS, 0, stream>>>(part, lutg);
    remap_kernel     <<<NCH * BPC, THREADS, 0, stream>>>(q, lutg, y);
}